// Round 3
// baseline (321.329 us; speedup 1.0000x reference)
//
#include <hip/hip_runtime.h>

// Problem: B=32, F_IN=64, F_OUT=64, D=512, K=64
// out[(b,o),d] = sum_{k,e} T[(b,o),(k,e)] * W[k,e,d],
// T[(b,o),(k,e)] = sum_i coeff[o,i,k] * x[b,i,e]
// GEMM shape: M=2048, N=512, Kdim=32768 (bf16 MFMA, fp32 accum)

#define KK 32768

typedef __attribute__((ext_vector_type(8))) short bf16x8;
typedef __attribute__((ext_vector_type(4))) float f32x4;

__device__ __forceinline__ unsigned short f2bf(float f) {
  unsigned int u = __float_as_uint(f);
  return (unsigned short)((u + 0x7FFFu + ((u >> 16) & 1u)) >> 16);  // RNE
}

__device__ __forceinline__ void gld16(void* lds, const void* g) {
  __builtin_amdgcn_global_load_lds((const __attribute__((address_space(1))) void*)g,
                                   (__attribute__((address_space(3))) void*)lds,
                                   16, 0, 0);
}

// ---- convert W fp32 [64][512(e)][512(d)] -> WbT bf16 [512(d)][64*512 (k,e)]
__global__ __launch_bounds__(256) void convW(const float* __restrict__ W,
                                             unsigned short* __restrict__ WbT) {
  __shared__ float tile[64][65];
  int bx = blockIdx.x;                 // 64 k * 8 et * 8 dt = 4096
  int k = bx >> 6, et = (bx >> 3) & 7, dt = bx & 7;
  int t = threadIdx.x;
  const float* src = W + ((size_t)k * 512 + (size_t)et * 64) * 512 + dt * 64;
  int rr = t >> 6, cc = t & 63;
#pragma unroll
  for (int p = 0; p < 16; p++) {
    int e = p * 4 + rr;
    tile[e][cc] = src[(size_t)e * 512 + cc];
  }
  __syncthreads();
  int dl = t >> 4, eg = t & 15;
#pragma unroll
  for (int p = 0; p < 4; p++) {
    int d = p * 16 + dl;
    ushort4 v;
    v.x = f2bf(tile[eg * 4 + 0][d]);
    v.y = f2bf(tile[eg * 4 + 1][d]);
    v.z = f2bf(tile[eg * 4 + 2][d]);
    v.w = f2bf(tile[eg * 4 + 3][d]);
    *(ushort4*)(WbT + (size_t)(dt * 64 + d) * KK + k * 512 + et * 64 + eg * 4) = v;
  }
}

// ---- convert x fp32 [32][64(i)][512(e)] -> xT bf16 [32][512(e)][64(i)] (LDS transpose)
__global__ __launch_bounds__(256) void convX(const float* __restrict__ x,
                                             unsigned short* __restrict__ xT) {
  __shared__ unsigned short lds[64 * 130];
  int bx = blockIdx.x;                  // 32 b * 4 ec = 128
  int b = bx >> 2, ec = bx & 3;
  int t = threadIdx.x;
  const float* src = x + (size_t)b * 32768 + ec * 128;
#pragma unroll
  for (int j = 0; j < 32; j++) {
    int idx = j * 256 + t;              // 64 i x 128 e
    int i = idx >> 7, e = idx & 127;
    lds[i * 130 + e] = f2bf(src[(size_t)i * 512 + e]);
  }
  __syncthreads();
  unsigned short* dst = xT + (size_t)b * 32768 + ec * 128 * 64;
#pragma unroll
  for (int j = 0; j < 32; j++) {
    int idx = j * 256 + t;              // 128 e x 64 i
    int e = idx >> 6, i = idx & 63;
    dst[idx] = lds[i * 130 + e];
  }
}

// ---- convert coeff fp32 [64(o)][64(i)][64(k)] -> cb bf16 [64(k)][64(o*64+i)] (LDS transpose)
__global__ __launch_bounds__(256) void convC(const float* __restrict__ c,
                                             unsigned short* __restrict__ cb) {
  __shared__ unsigned short lds[64 * 66];
  int rb = blockIdx.x;                  // 64 blocks over r = o*64+i
  int t = threadIdx.x;
  const float* src = c + (size_t)rb * 4096;
#pragma unroll
  for (int j = 0; j < 16; j++) {
    int idx = j * 256 + t;
    int r = idx >> 6, k = idx & 63;
    lds[r * 66 + k] = f2bf(src[idx]);
  }
  __syncthreads();
#pragma unroll
  for (int j = 0; j < 16; j++) {
    int idx = j * 256 + t;
    int k = idx >> 6, r = idx & 63;
    cb[(size_t)k * 4096 + rb * 64 + r] = lds[r * 66 + k];
  }
}

// ---- T kernel: Tb[(b*64+o)][(k*512+e)] = sum_i cb[k][o][i] * xT[b][e][i]
// block = (b, k, e-half of 256). MFMA; output staged in padded LDS, stored ushort4 (512B runs).
__global__ __launch_bounds__(256, 2) void tkern(const unsigned short* __restrict__ xT,
                                                const unsigned short* __restrict__ cb,
                                                unsigned short* __restrict__ Tb) {
  __shared__ char smem[40960];               // xe 32KB + ck 8KB; ot (33280B) aliases after use
  unsigned short* xe = (unsigned short*)smem;            // [256 e][64 i], XOR-swizzled chunks
  unsigned short* ck = (unsigned short*)(smem + 32768);  // [64 o][64 i], XOR-swizzled
  unsigned short* ot = (unsigned short*)smem;            // [64 o][pitch 260]
  int bx = blockIdx.x;                       // ((b*64 + k)*2 + eh) = 4096
  int eh = bx & 1, k = (bx >> 1) & 63, b = bx >> 7;
  int t = threadIdx.x;
  int srow = t >> 3, slot = t & 7;
  int cg = slot ^ (srow & 7);
  {
    const unsigned short* gx = xT + (size_t)b * 32768 + (size_t)eh * 16384 + srow * 64 + cg * 8;
#pragma unroll
    for (int j = 0; j < 8; j++)
      gld16((char*)xe + (j * 256 + t) * 16, gx + (size_t)j * 2048);
    const unsigned short* gc = cb + (size_t)k * 4096 + srow * 64 + cg * 8;
#pragma unroll
    for (int j = 0; j < 2; j++)
      gld16((char*)ck + (j * 256 + t) * 16, gc + (size_t)j * 2048);
  }
  __syncthreads();
  int wid = t >> 6, lane = t & 63, q = lane >> 4, l16 = lane & 15;
  f32x4 acc[4][4] = {};                      // [mf(o)][nf(e)]
  bf16x8 af[4][2];
#pragma unroll
  for (int mf = 0; mf < 4; mf++)
#pragma unroll
    for (int ks2 = 0; ks2 < 2; ks2++) {
      int row = mf * 16 + l16;
      int s2 = (ks2 * 4 + q) ^ (row & 7);
      af[mf][ks2] = *(const bf16x8*)(ck + row * 64 + s2 * 8);
    }
#pragma unroll
  for (int nf = 0; nf < 4; nf++) {
    int e = wid * 64 + nf * 16 + l16;
#pragma unroll
    for (int ks2 = 0; ks2 < 2; ks2++) {
      int s2 = (ks2 * 4 + q) ^ (e & 7);
      bf16x8 bfr = *(const bf16x8*)(xe + e * 64 + s2 * 8);
#pragma unroll
      for (int mf = 0; mf < 4; mf++)
        acc[mf][nf] = __builtin_amdgcn_mfma_f32_16x16x32_bf16(af[mf][ks2], bfr, acc[mf][nf], 0, 0, 0);
    }
  }
  __syncthreads();                           // xe/ck reads done; safe to alias ot
#pragma unroll
  for (int mf = 0; mf < 4; mf++)
#pragma unroll
    for (int nf = 0; nf < 4; nf++)
#pragma unroll
      for (int r = 0; r < 4; r++) {
        int o = mf * 16 + q * 4 + r;
        int e = wid * 64 + nf * 16 + l16;
        ot[o * 260 + e] = f2bf(acc[mf][nf][r]);
      }
  __syncthreads();
  unsigned short* gdst = Tb + (size_t)(b * 64) * KK + (size_t)k * 512 + (size_t)eh * 256;
#pragma unroll
  for (int j = 0; j < 16; j++) {
    int idx = j * 256 + t;                   // 64 o x 64 ushort4-slots
    int o = idx >> 6, c = idx & 63;
    *(ushort4*)(gdst + (size_t)o * KK + c * 4) = *(const ushort4*)(ot + o * 260 + c * 4);
  }
}

// ---- big GEMM: out[2048][512] += Tb[M][KK] * WbT[N][KK]^T
// 256x128 tile, waves 128x64 (8mf x 4nf), BK=32, double-buffered LDS, split-K=16.
__global__ __launch_bounds__(256, 2) void gemm_kern(const unsigned short* __restrict__ A,
                                                    const unsigned short* __restrict__ Bt,
                                                    float* __restrict__ out) {
  __shared__ unsigned short As[2][256 * 32];  // 16 KB x2
  __shared__ unsigned short Bs[2][128 * 32];  // 8 KB x2
  int bx = blockIdx.x;                        // ks*32 + mt*4 + nt = 512
  int nt = bx & 3, mt = (bx >> 2) & 7, ks = bx >> 5;
  int m0 = mt * 256, n0 = nt * 128;
  size_t k0 = (size_t)ks * 2048;
  int t = threadIdx.x;
  int wid = t >> 6, lane = t & 63, q = lane >> 4, l16 = lane & 15;
  int wm = (wid & 1) * 128, wn = (wid >> 1) * 64;
  f32x4 acc[8][4] = {};
  int srow = t >> 2;
  int cg = (t & 3) ^ (srow & 3);
  const unsigned short* ga = A + (size_t)(m0 + srow) * KK + k0 + cg * 8;
  const unsigned short* gb = Bt + (size_t)(n0 + srow) * KK + k0 + cg * 8;
  int sA = q ^ (l16 & 3);                     // frag slot (rows wm/wn/f*16 are mult of 4)
#pragma unroll 1
  for (int it = 0; it < 64; it++) {
    int cur = it & 1;
    if (it == 0) {
      // prologue stage into buf 0
#pragma unroll
      for (int j = 0; j < 4; j++)
        gld16((char*)As[0] + (j * 256 + t) * 16, ga + (size_t)(j * 64) * KK);
#pragma unroll
      for (int j = 0; j < 2; j++)
        gld16((char*)Bs[0] + (j * 256 + t) * 16, gb + (size_t)(j * 64) * KK);
      __syncthreads();
    }
    if (it < 63) {
      size_t ko = (size_t)(it + 1) * 32;
#pragma unroll
      for (int j = 0; j < 4; j++)
        gld16((char*)As[cur ^ 1] + (j * 256 + t) * 16, ga + (size_t)(j * 64) * KK + ko);
#pragma unroll
      for (int j = 0; j < 2; j++)
        gld16((char*)Bs[cur ^ 1] + (j * 256 + t) * 16, gb + (size_t)(j * 64) * KK + ko);
    }
    const unsigned short* as = As[cur];
    const unsigned short* bs = Bs[cur];
    bf16x8 af[8], bfr[4];
#pragma unroll
    for (int mf = 0; mf < 8; mf++)
      af[mf] = *(const bf16x8*)(as + (wm + mf * 16 + l16) * 32 + sA * 8);
#pragma unroll
    for (int nf = 0; nf < 4; nf++)
      bfr[nf] = *(const bf16x8*)(bs + (wn + nf * 16 + l16) * 32 + sA * 8);
#pragma unroll
    for (int mf = 0; mf < 8; mf++)
#pragma unroll
      for (int nf = 0; nf < 4; nf++)
        acc[mf][nf] = __builtin_amdgcn_mfma_f32_16x16x32_bf16(af[mf], bfr[nf], acc[mf][nf], 0, 0, 0);
    __syncthreads();
  }
#pragma unroll
  for (int mf = 0; mf < 8; mf++)
#pragma unroll
    for (int nf = 0; nf < 4; nf++)
#pragma unroll
      for (int r = 0; r < 4; r++)
        atomicAdd(&out[(size_t)(m0 + wm + mf * 16 + q * 4 + r) * 512 + n0 + wn + nf * 16 + l16],
                  acc[mf][nf][r]);
}

// ---- fp32 fallback (only if ws too small)
__global__ __launch_bounds__(256) void fallback_kern(const float* __restrict__ x,
                                                     const float* __restrict__ W,
                                                     const float* __restrict__ coeff,
                                                     float* __restrict__ out) {
  __shared__ float ev[64][129];
  int b = blockIdx.x >> 6, k = blockIdx.x & 63;
  int t = threadIdx.x, dl = t & 127, half = t >> 7;
  const float* xb = x + (size_t)b * 64 * 512;
  const float* Wk = W + (size_t)k * 512 * 512;
  for (int dc = 0; dc < 4; dc++) {
    int d = dc * 128 + dl;
    for (int i = half * 32; i < half * 32 + 32; i++) {
      float acc = 0.f;
      const float* xr = xb + (size_t)i * 512;
#pragma unroll 4
      for (int e = 0; e < 512; e++) acc += xr[e] * Wk[(size_t)e * 512 + d];
      ev[i][dl] = acc;
    }
    __syncthreads();
    for (int o = half * 32; o < half * 32 + 32; o++) {
      float s = 0.f;
#pragma unroll 8
      for (int i = 0; i < 64; i++) s += coeff[((size_t)o * 64 + i) * 64 + k] * ev[i][dl];
      atomicAdd(&out[((size_t)(b * 64 + o)) * 512 + d], s);
    }
    __syncthreads();
  }
}

extern "C" void kernel_launch(void* const* d_in, const int* in_sizes, int n_in,
                              void* d_out, int out_size, void* d_ws, size_t ws_size,
                              hipStream_t stream) {
  const float* x = (const float*)d_in[0];
  const float* W = (const float*)d_in[1];
  const float* coeff = (const float*)d_in[2];
  float* out = (float*)d_out;
  const size_t OFF_XT = 33554432;            // WbT: 512*32768*2
  const size_t OFF_CB = OFF_XT + 2097152;    // xT : 32*512*64*2
  const size_t OFF_TB = OFF_CB + 524288;     // cb : 64*64*64*2
  const size_t NEED = OFF_TB + 134217728;    // Tb : 2048*32768*2

  hipMemsetAsync(d_out, 0, (size_t)out_size * sizeof(float), stream);
  if (ws_size >= NEED) {
    unsigned short* WbT = (unsigned short*)d_ws;
    unsigned short* xT  = (unsigned short*)((char*)d_ws + OFF_XT);
    unsigned short* cb  = (unsigned short*)((char*)d_ws + OFF_CB);
    unsigned short* Tb  = (unsigned short*)((char*)d_ws + OFF_TB);
    convX<<<128, 256, 0, stream>>>(x, xT);
    convC<<<64, 256, 0, stream>>>(coeff, cb);
    convW<<<4096, 256, 0, stream>>>(W, WbT);
    tkern<<<4096, 256, 0, stream>>>(xT, cb, Tb);
    gemm_kern<<<512, 256, 0, stream>>>(Tb, WbT, out);
  } else {
    fallback_kern<<<2048, 256, 0, stream>>>(x, W, coeff, out);
  }
}

// Round 4
// 246.939 us; speedup vs baseline: 1.3012x; 1.3012x over previous
//
#include <hip/hip_runtime.h>

// Problem: B=32, F_IN=64, F_OUT=64, D=512, K=64
// out[(b,o),d] = sum_{k,e} T[(b,o),(k,e)] * W[k,e,d],
// T[(b,o),(k,e)] = sum_i coeff[o,i,k] * x[b,i,e]
// GEMM shape: M=2048, N=512, Kdim=32768 (bf16 MFMA, fp32 accum)

#define KK 32768

typedef __attribute__((ext_vector_type(8))) short bf16x8;
typedef __attribute__((ext_vector_type(4))) float f32x4;

__device__ __forceinline__ unsigned short f2bf(float f) {
  unsigned int u = __float_as_uint(f);
  return (unsigned short)((u + 0x7FFFu + ((u >> 16) & 1u)) >> 16);  // RNE
}

__device__ __forceinline__ void gld16(void* lds, const void* g) {
  __builtin_amdgcn_global_load_lds((const __attribute__((address_space(1))) void*)g,
                                   (__attribute__((address_space(3))) void*)lds,
                                   16, 0, 0);
}

// ---- convert W fp32 [64][512(e)][512(d)] -> WbT bf16 [512(d)][64*512 (k,e)]
__global__ __launch_bounds__(256) void convW(const float* __restrict__ W,
                                             unsigned short* __restrict__ WbT) {
  __shared__ float tile[64][65];
  int bx = blockIdx.x;                 // 64 k * 8 et * 8 dt = 4096
  int k = bx >> 6, et = (bx >> 3) & 7, dt = bx & 7;
  int t = threadIdx.x;
  const float* src = W + ((size_t)k * 512 + (size_t)et * 64) * 512 + dt * 64;
  int rr = t >> 6, cc = t & 63;
#pragma unroll
  for (int p = 0; p < 16; p++) {
    int e = p * 4 + rr;
    tile[e][cc] = src[(size_t)e * 512 + cc];
  }
  __syncthreads();
  int dl = t >> 4, eg = t & 15;
#pragma unroll
  for (int p = 0; p < 4; p++) {
    int d = p * 16 + dl;
    ushort4 v;
    v.x = f2bf(tile[eg * 4 + 0][d]);
    v.y = f2bf(tile[eg * 4 + 1][d]);
    v.z = f2bf(tile[eg * 4 + 2][d]);
    v.w = f2bf(tile[eg * 4 + 3][d]);
    *(ushort4*)(WbT + (size_t)(dt * 64 + d) * KK + k * 512 + et * 64 + eg * 4) = v;
  }
}

// ---- convert x fp32 [32][64(i)][512(e)] -> xT bf16 [32][512(e)][64(i)] (LDS transpose)
__global__ __launch_bounds__(256) void convX(const float* __restrict__ x,
                                             unsigned short* __restrict__ xT) {
  __shared__ unsigned short lds[64 * 130];
  int bx = blockIdx.x;                  // 32 b * 4 ec = 128
  int b = bx >> 2, ec = bx & 3;
  int t = threadIdx.x;
  const float* src = x + (size_t)b * 32768 + ec * 128;
#pragma unroll
  for (int j = 0; j < 32; j++) {
    int idx = j * 256 + t;              // 64 i x 128 e
    int i = idx >> 7, e = idx & 127;
    lds[i * 130 + e] = f2bf(src[(size_t)i * 512 + e]);
  }
  __syncthreads();
  unsigned short* dst = xT + (size_t)b * 32768 + ec * 128 * 64;
#pragma unroll
  for (int j = 0; j < 32; j++) {
    int idx = j * 256 + t;              // 128 e x 64 i
    int e = idx >> 6, i = idx & 63;
    dst[idx] = lds[i * 130 + e];
  }
}

// ---- convert coeff fp32 [64(o)][64(i)][64(k)] -> cb bf16 [64(k)][64(o*64+i)] (LDS transpose)
__global__ __launch_bounds__(256) void convC(const float* __restrict__ c,
                                             unsigned short* __restrict__ cb) {
  __shared__ unsigned short lds[64 * 66];
  int rb = blockIdx.x;                  // 64 blocks over r = o*64+i
  int t = threadIdx.x;
  const float* src = c + (size_t)rb * 4096;
#pragma unroll
  for (int j = 0; j < 16; j++) {
    int idx = j * 256 + t;
    int r = idx >> 6, k = idx & 63;
    lds[r * 66 + k] = f2bf(src[idx]);
  }
  __syncthreads();
#pragma unroll
  for (int j = 0; j < 16; j++) {
    int idx = j * 256 + t;
    int k = idx >> 6, r = idx & 63;
    cb[(size_t)k * 4096 + rb * 64 + r] = lds[r * 66 + k];
  }
}

// ---- T kernel v3: Tb[(b*64+o)][(k*512+e)] = sum_i cb[k][o][i] * xT[b][e][i]
// block = (b, k-quad, e-quarter 128). xe staged ONCE, reused over 4 k-words.
// LDS 49.6 KB -> 3 blocks/CU. ck double-buffered; stores in 256B runs via ot.
__global__ __launch_bounds__(256, 2) void tkern(const unsigned short* __restrict__ xT,
                                                const unsigned short* __restrict__ cb,
                                                unsigned short* __restrict__ Tb) {
  __shared__ unsigned short xe[128 * 64];    // 16 KB, XOR-swizzled chunks
  __shared__ unsigned short ckb[2][64 * 64]; // 8 KB x2, XOR-swizzled
  __shared__ unsigned short ot[64 * 132];    // 16.9 KB, store staging
  int bx = blockIdx.x;                       // 32 b * 16 kq * 4 eq = 2048
  int eq = bx & 3, kq = (bx >> 2) & 15, b = bx >> 6;
  int t = threadIdx.x;
  // stage xe: 128 e rows x 8 chunks of 16B
  {
    const unsigned short* gx = xT + (size_t)b * 32768 + (size_t)eq * 8192;
#pragma unroll
    for (int j = 0; j < 4; j++) {
      int idx = j * 256 + t;
      int e = idx >> 3, cg = (idx & 7) ^ (e & 7);
      gld16((char*)xe + idx * 16, gx + e * 64 + cg * 8);
    }
    // stage ck[0] for k = kq*4
    const unsigned short* gc = cb + (size_t)(kq * 4) * 4096;
#pragma unroll
    for (int j = 0; j < 2; j++) {
      int idx = j * 256 + t;
      int o = idx >> 3, cg = (idx & 7) ^ (o & 7);
      gld16((char*)ckb[0] + idx * 16, gc + o * 64 + cg * 8);
    }
  }
  int wid = t >> 6, lane = t & 63, q = lane >> 4, l16 = lane & 15;
  size_t mbase = (size_t)(b * 64) * KK;
#pragma unroll 1
  for (int kj = 0; kj < 4; kj++) {
    int cur = kj & 1;
    __syncthreads();   // ck[cur] ready; ot free (prev stores done)
    if (kj < 3) {      // issue next ck stage early (drained by next barrier)
      const unsigned short* gc = cb + (size_t)(kq * 4 + kj + 1) * 4096;
#pragma unroll
      for (int j = 0; j < 2; j++) {
        int idx = j * 256 + t;
        int o = idx >> 3, cg = (idx & 7) ^ (o & 7);
        gld16((char*)ckb[cur ^ 1] + idx * 16, gc + o * 64 + cg * 8);
      }
    }
    const unsigned short* ck = ckb[cur];
    f32x4 acc[4][2] = {};                    // wave-tile: 64 o x 32 e
    bf16x8 af[4][2], bfr[2][2];
#pragma unroll
    for (int mf = 0; mf < 4; mf++)
#pragma unroll
      for (int ks2 = 0; ks2 < 2; ks2++) {
        int row = mf * 16 + l16;
        int s2 = (ks2 * 4 + q) ^ (row & 7);
        af[mf][ks2] = *(const bf16x8*)(ck + row * 64 + s2 * 8);
      }
#pragma unroll
    for (int nf = 0; nf < 2; nf++) {
      int e = wid * 32 + nf * 16 + l16;
#pragma unroll
      for (int ks2 = 0; ks2 < 2; ks2++) {
        int s2 = (ks2 * 4 + q) ^ (e & 7);
        bfr[nf][ks2] = *(const bf16x8*)(xe + e * 64 + s2 * 8);
      }
    }
#pragma unroll
    for (int mf = 0; mf < 4; mf++)
#pragma unroll
      for (int nf = 0; nf < 2; nf++)
#pragma unroll
        for (int ks2 = 0; ks2 < 2; ks2++)
          acc[mf][nf] = __builtin_amdgcn_mfma_f32_16x16x32_bf16(af[mf][ks2], bfr[nf][ks2],
                                                                acc[mf][nf], 0, 0, 0);
    // C-layout -> ot: row(o)=q*4+r, col(e)=l16
#pragma unroll
    for (int mf = 0; mf < 4; mf++)
#pragma unroll
      for (int nf = 0; nf < 2; nf++)
#pragma unroll
        for (int r = 0; r < 4; r++) {
          int o = mf * 16 + q * 4 + r;
          int e = wid * 32 + nf * 16 + l16;
          ot[o * 132 + e] = f2bf(acc[mf][nf][r]);
        }
    __syncthreads();   // ot ready
    unsigned short* gdst = Tb + mbase + (size_t)(kq * 4 + kj) * 512 + eq * 128;
#pragma unroll
    for (int j = 0; j < 8; j++) {
      int idx = j * 256 + t;                 // 64 o x 32 ushort4-slots
      int o = idx >> 5, c = idx & 31;
      *(ushort4*)(gdst + (size_t)o * KK + c * 4) = *(const ushort4*)(ot + o * 132 + c * 4);
    }
  }
}

// ---- big GEMM (R2 proven config): out[2048][512] += Tb[M][KK] * WbT[N][KK]^T
// 128x128 tile, BK=64, split-K=16 (1024 blocks), single-buffer, 128B-pitch XOR swizzle.
__global__ __launch_bounds__(256, 4) void gemm_kern(const unsigned short* __restrict__ A,
                                                    const unsigned short* __restrict__ Bt,
                                                    float* __restrict__ out) {
  __shared__ unsigned short As[128 * 64];   // 16 KB, row pitch 128 B (8 chunks of 16 B)
  __shared__ unsigned short Bs[128 * 64];   // 16 KB
  int bx = blockIdx.x;                      // 16 ks * 4 nt * 16 mt = 1024
  int ks = bx & 15, nt = (bx >> 4) & 3, mt = bx >> 6;
  int m0 = mt * 128, n0 = nt * 128, k0 = ks * 2048;
  int t = threadIdx.x;
  int wid = t >> 6, lane = t & 63, q = lane >> 4, l16 = lane & 15;
  int wm = (wid & 1) * 64, wn = (wid >> 1) * 64;
  f32x4 acc[4][4] = {};
  int srow = t >> 3;
  int cg = (t & 7) ^ (srow & 7);
  const char* gabase = (const char*)(A + (size_t)m0 * KK + k0) + (size_t)srow * 65536 + cg * 16;
  const char* gbbase = (const char*)(Bt + (size_t)n0 * KK + k0) + (size_t)srow * 65536 + cg * 16;
  int sw0 = q ^ (l16 & 7);
  int sw1 = (4 | q) ^ (l16 & 7);
#pragma unroll 1
  for (int kc = 0; kc < 2048; kc += 64) {
    const char* ga = gabase + (size_t)kc * 2;
    const char* gb = gbbase + (size_t)kc * 2;
#pragma unroll
    for (int j = 0; j < 4; j++) {
      gld16((char*)As + (j * 256 + t) * 16, ga + (size_t)j * 32 * 65536);
      gld16((char*)Bs + (j * 256 + t) * 16, gb + (size_t)j * 32 * 65536);
    }
    __syncthreads();
#pragma unroll
    for (int ks2 = 0; ks2 < 2; ks2++) {
      int slot = ks2 ? sw1 : sw0;
      bf16x8 af[4], bfr[4];
#pragma unroll
      for (int fr = 0; fr < 4; fr++)
        af[fr] = *(const bf16x8*)(As + (wm + fr * 16 + l16) * 64 + slot * 8);
#pragma unroll
      for (int fc = 0; fc < 4; fc++)
        bfr[fc] = *(const bf16x8*)(Bs + (wn + fc * 16 + l16) * 64 + slot * 8);
#pragma unroll
      for (int fr = 0; fr < 4; fr++)
#pragma unroll
        for (int fc = 0; fc < 4; fc++)
          acc[fr][fc] = __builtin_amdgcn_mfma_f32_16x16x32_bf16(af[fr], bfr[fc], acc[fr][fc], 0, 0, 0);
    }
    __syncthreads();
  }
#pragma unroll
  for (int fr = 0; fr < 4; fr++)
#pragma unroll
    for (int fc = 0; fc < 4; fc++)
#pragma unroll
      for (int r = 0; r < 4; r++)
        atomicAdd(&out[(size_t)(m0 + wm + fr * 16 + q * 4 + r) * 512 + n0 + wn + fc * 16 + l16],
                  acc[fr][fc][r]);
}

// ---- fp32 fallback (only if ws too small)
__global__ __launch_bounds__(256) void fallback_kern(const float* __restrict__ x,
                                                     const float* __restrict__ W,
                                                     const float* __restrict__ coeff,
                                                     float* __restrict__ out) {
  __shared__ float ev[64][129];
  int b = blockIdx.x >> 6, k = blockIdx.x & 63;
  int t = threadIdx.x, dl = t & 127, half = t >> 7;
  const float* xb = x + (size_t)b * 64 * 512;
  const float* Wk = W + (size_t)k * 512 * 512;
  for (int dc = 0; dc < 4; dc++) {
    int d = dc * 128 + dl;
    for (int i = half * 32; i < half * 32 + 32; i++) {
      float acc = 0.f;
      const float* xr = xb + (size_t)i * 512;
#pragma unroll 4
      for (int e = 0; e < 512; e++) acc += xr[e] * Wk[(size_t)e * 512 + d];
      ev[i][dl] = acc;
    }
    __syncthreads();
    for (int o = half * 32; o < half * 32 + 32; o++) {
      float s = 0.f;
#pragma unroll 8
      for (int i = 0; i < 64; i++) s += coeff[((size_t)o * 64 + i) * 64 + k] * ev[i][dl];
      atomicAdd(&out[((size_t)(b * 64 + o)) * 512 + d], s);
    }
    __syncthreads();
  }
}

extern "C" void kernel_launch(void* const* d_in, const int* in_sizes, int n_in,
                              void* d_out, int out_size, void* d_ws, size_t ws_size,
                              hipStream_t stream) {
  const float* x = (const float*)d_in[0];
  const float* W = (const float*)d_in[1];
  const float* coeff = (const float*)d_in[2];
  float* out = (float*)d_out;
  const size_t OFF_XT = 33554432;            // WbT: 512*32768*2
  const size_t OFF_CB = OFF_XT + 2097152;    // xT : 32*512*64*2
  const size_t OFF_TB = OFF_CB + 524288;     // cb : 64*64*64*2
  const size_t NEED = OFF_TB + 134217728;    // Tb : 2048*32768*2

  hipMemsetAsync(d_out, 0, (size_t)out_size * sizeof(float), stream);
  if (ws_size >= NEED) {
    unsigned short* WbT = (unsigned short*)d_ws;
    unsigned short* xT  = (unsigned short*)((char*)d_ws + OFF_XT);
    unsigned short* cb  = (unsigned short*)((char*)d_ws + OFF_CB);
    unsigned short* Tb  = (unsigned short*)((char*)d_ws + OFF_TB);
    convX<<<128, 256, 0, stream>>>(x, xT);
    convC<<<64, 256, 0, stream>>>(coeff, cb);
    convW<<<4096, 256, 0, stream>>>(W, WbT);
    tkern<<<2048, 256, 0, stream>>>(xT, cb, Tb);
    gemm_kern<<<1024, 256, 0, stream>>>(Tb, WbT, out);
  } else {
    fallback_kern<<<2048, 256, 0, stream>>>(x, W, coeff, out);
  }
}